// Round 3
// baseline (166.610 us; speedup 1.0000x reference)
//
#include <hip/hip_runtime.h>

#define N_BINS 30
#define NCLASS 10
#define BLOCK 256
#define ROWS_PER_CHUNK 512          // 512 rows * 40B = 20KB staged per chunk
#define GRID 1792                   // 7 blocks/CU * 256 CU

// Workspace (u64 slots): [0..30) g_conf  fixed-point sum (2^20 scale)
//                        [30..60) g_cc   (count<<32 | correct)
//                        [60]     done-counter (as uint in low word)

__global__ void ece_zero_ws(unsigned long long* g) {
    int i = threadIdx.x;
    if (i < 2 * N_BINS + 1) g[i] = 0ull;
}

__device__ __forceinline__ void row_stats(const float* __restrict__ v,
                                          int lbl, int& bin,
                                          unsigned long long& pack) {
    float conf = v[0];
    int pred = 0;
    #pragma unroll
    for (int j = 1; j < NCLASS; ++j) {
        if (v[j] > conf) { conf = v[j]; pred = j; }
    }
    int b = (int)ceilf(conf * (float)N_BINS) - 1;
    bin = min(max(b, 0), N_BINS - 1);
    unsigned int fx = (unsigned int)(conf * 1048576.0f + 0.5f);   // 2^20 scale
    unsigned long long acc = (pred == lbl) ? 1ull : 0ull;
    pack = ((unsigned long long)fx << 32) | (1ull << 16) | acc;
}

__global__ __launch_bounds__(BLOCK) void ece_hist(
        const float* __restrict__ sm,
        const int*   __restrict__ labels,
        int n,
        unsigned long long* __restrict__ g_conf,
        unsigned long long* __restrict__ g_cc,
        unsigned int* __restrict__ done,
        float* __restrict__ out) {
    __shared__ float4 s_rows4[ROWS_PER_CHUNK * NCLASS / 4];   // 20 KB
    __shared__ unsigned long long s_hist[4][N_BINS];          // per-wave copies
    __shared__ float s_gap[N_BINS];
    __shared__ unsigned int s_last;

    float* s_rows = reinterpret_cast<float*>(s_rows4);
    const int tid = threadIdx.x;
    const int wid = tid >> 6;

    for (int i = tid; i < 4 * N_BINS; i += BLOCK)
        (&s_hist[0][0])[i] = 0ull;
    __syncthreads();

    const int nchunks = (n + ROWS_PER_CHUNK - 1) / ROWS_PER_CHUNK;
    for (int c = blockIdx.x; c < nchunks; c += gridDim.x) {
        const long long base = (long long)c * ROWS_PER_CHUNK;
        const long long remll = (long long)n - base;
        const int rem = remll < ROWS_PER_CHUNK ? (int)remll : ROWS_PER_CHUNK;
        const int nfloats = rem * NCLASS;

        // ---- coalesced stage: lane-contiguous float4 global -> LDS ----
        const float4* src = reinterpret_cast<const float4*>(sm + base * NCLASS);
        #pragma unroll
        for (int k = 0; k < 5; ++k) {
            int f = tid + k * BLOCK;
            if (f * 4 + 3 < nfloats) s_rows4[f] = src[f];
        }
        if (tid == 0) {                       // 0-3 leftover floats (generic guard)
            int start = (nfloats / 4) * 4;
            for (int j = start; j < nfloats; ++j)
                s_rows[j] = sm[base * NCLASS + j];
        }
        __syncthreads();

        // ---- compute rows tid and tid+256 ----
        int b0 = -1, b1 = -2;
        unsigned long long p0 = 0, p1 = 0;
        bool v0 = false, v1 = false;
        if (tid < rem) {
            float v[NCLASS];
            const float* row = s_rows + tid * NCLASS;
            #pragma unroll
            for (int h = 0; h < 5; ++h) {
                float2 q = *reinterpret_cast<const float2*>(row + 2 * h);
                v[2*h] = q.x; v[2*h+1] = q.y;
            }
            row_stats(v, labels[base + tid], b0, p0); v0 = true;
        }
        if (tid + BLOCK < rem) {
            float v[NCLASS];
            const float* row = s_rows + (tid + BLOCK) * NCLASS;
            #pragma unroll
            for (int h = 0; h < 5; ++h) {
                float2 q = *reinterpret_cast<const float2*>(row + 2 * h);
                v[2*h] = q.x; v[2*h+1] = q.y;
            }
            row_stats(v, labels[base + tid + BLOCK], b1, p1); v1 = true;
        }

        if (v1 && b1 == b0) { p0 += p1; v1 = false; }
        if (v0) atomicAdd(&s_hist[wid][b0], p0);
        if (v1) atomicAdd(&s_hist[wid][b1], p1);

        __syncthreads();   // before next chunk overwrites s_rows
    }

    // ---- flush block totals once ----
    if (tid < N_BINS) {
        unsigned long long h = s_hist[0][tid] + s_hist[1][tid]
                             + s_hist[2][tid] + s_hist[3][tid];
        if (h) {
            unsigned long long fxsum = h >> 32;
            unsigned long long cnt   = (h >> 16) & 0xFFFFull;
            unsigned long long acc   = h & 0xFFFFull;
            atomicAdd(&g_conf[tid], fxsum);
            atomicAdd(&g_cc[tid], (cnt << 32) | acc);
        }
    }
    __threadfence();
    __syncthreads();

    if (tid == 0) {
        unsigned int old = atomicAdd(done, 1u);
        s_last = (old == gridDim.x - 1) ? 1u : 0u;
    }
    __syncthreads();

    // ---- last block finalizes ----
    if (s_last) {
        if (tid < N_BINS) {
            __threadfence();
            unsigned long long cc = atomicAdd(&g_cc[tid], 0ull);    // coherent read
            unsigned long long cf = atomicAdd(&g_conf[tid], 0ull);
            unsigned int cnt = (unsigned int)(cc >> 32);
            unsigned int cor = (unsigned int)(cc & 0xFFFFFFFFull);
            float gap = 0.0f;
            if (cnt) {
                float fcnt = (float)cnt;
                float avg  = (float)((double)cf * (1.0 / 1048576.0)) / fcnt;
                float acc  = (float)cor / fcnt;
                gap = fabsf(avg - acc) * (fcnt / (float)n);
            }
            s_gap[tid] = gap;
        }
        __syncthreads();
        if (tid == 0) {
            float e = 0.0f;
            for (int b = 0; b < N_BINS; ++b) e += s_gap[b];
            out[0] = e;
        }
    }
}

extern "C" void kernel_launch(void* const* d_in, const int* in_sizes, int n_in,
                              void* d_out, int out_size, void* d_ws, size_t ws_size,
                              hipStream_t stream) {
    const float* sm   = (const float*)d_in[0];
    const int* labels = (const int*)d_in[1];
    const int n = in_sizes[1];   // 4,000,000 rows

    unsigned long long* g = (unsigned long long*)d_ws;
    unsigned long long* g_conf = g;
    unsigned long long* g_cc   = g + N_BINS;
    unsigned int* done = (unsigned int*)(g + 2 * N_BINS);

    ece_zero_ws<<<1, 64, 0, stream>>>(g);
    ece_hist<<<GRID, BLOCK, 0, stream>>>(sm, labels, n, g_conf, g_cc, done,
                                         (float*)d_out);
}